// Round 4
// baseline (502.989 us; speedup 1.0000x reference)
//
#include <hip/hip_runtime.h>

#define EDGES        800000
#define IN_F         64
#define HID          128
#define TPB          256          // 4 waves per WG
#define EPW          32           // edges per wave (two 16-edge strips)
#define EDGES_PER_WG 128
#define NWG          (EDGES / EDGES_PER_WG)   // 6250

typedef _Float16 half8  __attribute__((ext_vector_type(8)));
typedef _Float16 half4  __attribute__((ext_vector_type(4)));
typedef __fp16   fp16x2 __attribute__((ext_vector_type(2)));   // cvt_pkrtz return type
typedef float    f32x4  __attribute__((ext_vector_type(4)));

// f16 weights, rewritten by a prologue kernel every call.
__device__ __align__(16) _Float16 g_w1[HID * IN_F];   // [h'][k] row-major
__device__ __align__(16) _Float16 g_w2[HID * HID];
__device__ __align__(16) _Float16 g_w3[HID * HID];

__global__ void cvt_weights(const float* __restrict__ W1,
                            const float* __restrict__ W2,
                            const float* __restrict__ W3) {
    int i = blockIdx.x * TPB + threadIdx.x;            // grid 64*256 = 16384
    if (i < HID * IN_F) g_w1[i] = (_Float16)W1[i];
    g_w2[i] = (_Float16)W2[i];
    g_w3[i] = (_Float16)W3[i];
}

__device__ __forceinline__ float fast_tanh(float x) {
    float e = __builtin_amdgcn_exp2f(2.8853900817779268f * x);   // e^{2x}
    return 1.0f - 2.0f * __builtin_amdgcn_rcpf(e + 1.0f);
}
__device__ __forceinline__ float fast_sigmoid(float x) {
    return __builtin_amdgcn_rcpf(1.0f + __builtin_amdgcn_exp2f(-1.4426950408889634f * x));
}

__device__ __forceinline__ half4 tanh_pack4(f32x4 a) {
    fp16x2 lo = __builtin_amdgcn_cvt_pkrtz(fast_tanh(a[0]), fast_tanh(a[1]));
    fp16x2 hi = __builtin_amdgcn_cvt_pkrtz(fast_tanh(a[2]), fast_tanh(a[3]));
    half4 r;
    r[0] = (_Float16)lo[0]; r[1] = (_Float16)lo[1];
    r[2] = (_Float16)hi[0]; r[3] = (_Float16)hi[1];
    return r;
}

__device__ __forceinline__ half8 pack8(float4 a, float4 b) {
    fp16x2 p0 = __builtin_amdgcn_cvt_pkrtz(a.x, a.y);
    fp16x2 p1 = __builtin_amdgcn_cvt_pkrtz(a.z, a.w);
    fp16x2 p2 = __builtin_amdgcn_cvt_pkrtz(b.x, b.y);
    fp16x2 p3 = __builtin_amdgcn_cvt_pkrtz(b.z, b.w);
    half8 h;
    h[0]=(_Float16)p0[0]; h[1]=(_Float16)p0[1]; h[2]=(_Float16)p1[0]; h[3]=(_Float16)p1[1];
    h[4]=(_Float16)p2[0]; h[5]=(_Float16)p2[1]; h[6]=(_Float16)p3[0]; h[7]=(_Float16)p3[1];
    return h;
}

#define MFMA(a, b, c) __builtin_amdgcn_mfma_f32_16x16x32_f16((a), (b), (c), 0, 0, 0)

// D = W(A) x Act(B); D gives 4 contiguous h' per lane at fixed edge.
// H tile lives in wave-private LDS, XOR-swizzled on 16B blocks:
//   half addr(e, c) = e*128 + (((c>>3) ^ (e&7)) << 3) + (c&7)
// write (it): c = it*16 + q*4 -> blk = 2it + (q>>1), off = (q&1)*4   (b64)
// read  (t):  c = t*32 + q*8 -> blk = 4t + q,       off = 0         (b128)
// Both sides swizzle identically -> correct; banks spread over all 32.
// H is wave-private; intra-wave LDS ordering -> no __syncthreads.
__global__ __launch_bounds__(TPB, 4)
void mlp_fused(const float* __restrict__ ea,
               const float* __restrict__ b1,
               const float* __restrict__ b2,
               const float* __restrict__ b3,
               const float* __restrict__ w4,
               const float* __restrict__ b4,
               float* __restrict__ out) {
    __shared__ _Float16 H[4][EPW * HID];   // 32768 B -> 5 WG/CU possible

    const int tid  = threadIdx.x;
    const int w    = tid >> 6;
    const int lane = tid & 63;
    const int l16  = lane & 15;
    const int q    = lane >> 4;            // 0..3
    const int ebase = blockIdx.x * EDGES_PER_WG + w * EPW;
    _Float16* Hw = H[w];

    const int sw  = l16 & 7;               // swizzle key (same for both strips)
    const int wq  = q >> 1;
    const int wo  = (q & 1) * 4;
    const int row0 = l16 * HID, row1 = (16 + l16) * HID;

    // Per-lane weight base pointers (row l16, k-offset q*8)
    const _Float16* w1p = g_w1 + l16 * IN_F + q * 8;
    const _Float16* w2p = g_w2 + l16 * HID + q * 8;
    const _Float16* w3p = g_w3 + l16 * HID + q * 8;

    // ---------------- Layer 1 inputs: edges -> f16 B-frags ----------------
    half8 bf[2][4];                        // [strip][t] (L1 uses t=0,1)
    #pragma unroll
    for (int s = 0; s < 2; ++s) {
        #pragma unroll
        for (int t = 0; t < 2; ++t) {
            const float* p = ea + (ebase + s * 16 + l16) * IN_F + t * 32 + q * 8;
            bf[s][t] = pack8(((const float4*)p)[0], ((const float4*)p)[1]);
        }
    }

    half8  ac[4], an[4];                   // current / next weight frags
    float4 bc, bn;                         // current / next bias slice

    // ---------------- Layer 1 (K=64: t=0,1), 1-deep prefetch ----------------
    bc    = *(const float4*)(b1 + q * 4);
    ac[0] = *(const half8*)(w1p);
    ac[1] = *(const half8*)(w1p + 32);
    #pragma unroll
    for (int it = 0; it < 8; ++it) {
        if (it < 7) {
            bn    = *(const float4*)(b1 + (it + 1) * 16 + q * 4);
            an[0] = *(const half8*)(w1p + (it + 1) * 16 * IN_F);
            an[1] = *(const half8*)(w1p + (it + 1) * 16 * IN_F + 32);
        } else {                            // prefetch layer-2 it0 (t0,t1)
            bn    = *(const float4*)(b2 + q * 4);
            an[0] = *(const half8*)(w2p);
            an[1] = *(const half8*)(w2p + 32);
        }
        f32x4 acc0, acc1;
        acc0[0]=bc.x; acc0[1]=bc.y; acc0[2]=bc.z; acc0[3]=bc.w;
        acc1 = acc0;
        acc0 = MFMA(ac[0], bf[0][0], acc0); acc0 = MFMA(ac[1], bf[0][1], acc0);
        acc1 = MFMA(ac[0], bf[1][0], acc1); acc1 = MFMA(ac[1], bf[1][1], acc1);
        const int blk = ((2 * it + wq) ^ sw) << 3;
        *(half4*)&Hw[row0 + blk + wo] = tanh_pack4(acc0);
        *(half4*)&Hw[row1 + blk + wo] = tanh_pack4(acc1);
        ac[0] = an[0]; ac[1] = an[1]; bc = bn;
    }

    // ---------------- Layer 2 (K=128: t=0..3) ----------------
    ac[2] = *(const half8*)(w2p + 64);
    ac[3] = *(const half8*)(w2p + 96);
    #pragma unroll
    for (int s = 0; s < 2; ++s)
        #pragma unroll
        for (int t = 0; t < 4; ++t)
            bf[s][t] = *(const half8*)&Hw[(s * 16 + l16) * HID + (((4 * t + q) ^ sw) << 3)];
    #pragma unroll
    for (int it = 0; it < 8; ++it) {
        if (it < 7) {
            bn = *(const float4*)(b2 + (it + 1) * 16 + q * 4);
            #pragma unroll
            for (int t = 0; t < 4; ++t)
                an[t] = *(const half8*)(w2p + (it + 1) * 16 * HID + t * 32);
        } else {                            // prefetch layer-3 it0
            bn = *(const float4*)(b3 + q * 4);
            #pragma unroll
            for (int t = 0; t < 4; ++t)
                an[t] = *(const half8*)(w3p + t * 32);
        }
        f32x4 acc0, acc1;
        acc0[0]=bc.x; acc0[1]=bc.y; acc0[2]=bc.z; acc0[3]=bc.w;
        acc1 = acc0;
        #pragma unroll
        for (int t = 0; t < 4; ++t) {
            acc0 = MFMA(ac[t], bf[0][t], acc0);
            acc1 = MFMA(ac[t], bf[1][t], acc1);
        }
        const int blk = ((2 * it + wq) ^ sw) << 3;
        *(half4*)&Hw[row0 + blk + wo] = tanh_pack4(acc0);
        *(half4*)&Hw[row1 + blk + wo] = tanh_pack4(acc1);
        #pragma unroll
        for (int t = 0; t < 4; ++t) ac[t] = an[t];
        bc = bn;
    }

    // ---------------- Layer 3 + fused layer-4 dot ----------------
    float4 wc, wn;
    wc = *(const float4*)(w4 + q * 4);
    #pragma unroll
    for (int s = 0; s < 2; ++s)
        #pragma unroll
        for (int t = 0; t < 4; ++t)
            bf[s][t] = *(const half8*)&Hw[(s * 16 + l16) * HID + (((4 * t + q) ^ sw) << 3)];
    float p0 = 0.0f, p1 = 0.0f;
    #pragma unroll
    for (int it = 0; it < 8; ++it) {
        if (it < 7) {
            bn = *(const float4*)(b3 + (it + 1) * 16 + q * 4);
            wn = *(const float4*)(w4 + (it + 1) * 16 + q * 4);
            #pragma unroll
            for (int t = 0; t < 4; ++t)
                an[t] = *(const half8*)(w3p + (it + 1) * 16 * HID + t * 32);
        }
        f32x4 acc0, acc1;
        acc0[0]=bc.x; acc0[1]=bc.y; acc0[2]=bc.z; acc0[3]=bc.w;
        acc1 = acc0;
        #pragma unroll
        for (int t = 0; t < 4; ++t) {
            acc0 = MFMA(ac[t], bf[0][t], acc0);
            acc1 = MFMA(ac[t], bf[1][t], acc1);
        }
        p0 += fast_tanh(acc0[0]) * wc.x + fast_tanh(acc0[1]) * wc.y
            + fast_tanh(acc0[2]) * wc.z + fast_tanh(acc0[3]) * wc.w;
        p1 += fast_tanh(acc1[0]) * wc.x + fast_tanh(acc1[1]) * wc.y
            + fast_tanh(acc1[2]) * wc.z + fast_tanh(acc1[3]) * wc.w;
        if (it < 7) {
            #pragma unroll
            for (int t = 0; t < 4; ++t) ac[t] = an[t];
            bc = bn; wc = wn;
        }
    }
    // Sum over hidden: partials live in the 4 lanes sharing l16 (q = 0..3).
    p0 += __shfl_xor(p0, 16, 64);  p0 += __shfl_xor(p0, 32, 64);
    p1 += __shfl_xor(p1, 16, 64);  p1 += __shfl_xor(p1, 32, 64);
    const float bb = b4[0];
    if (lane < 16)      out[ebase + lane] = fast_sigmoid(p0 + bb);
    else if (lane < 32) out[ebase + lane] = fast_sigmoid(p1 + bb);  // strip-1 edges 16..31
}

extern "C" void kernel_launch(void* const* d_in, const int* in_sizes, int n_in,
                              void* d_out, int out_size, void* d_ws, size_t ws_size,
                              hipStream_t stream) {
    // setup_inputs order: x, edge_index, edge_attr, W1,b1, W2,b2, W3,b3, W4,b4
    const float* ea = (const float*)d_in[2];
    const float* W1 = (const float*)d_in[3];
    const float* b1 = (const float*)d_in[4];
    const float* W2 = (const float*)d_in[5];
    const float* b2 = (const float*)d_in[6];
    const float* W3 = (const float*)d_in[7];
    const float* b3 = (const float*)d_in[8];
    const float* W4 = (const float*)d_in[9];
    const float* b4 = (const float*)d_in[10];
    float* out = (float*)d_out;

    hipLaunchKernelGGL(cvt_weights, dim3((HID * HID) / TPB), dim3(TPB), 0, stream,
                       W1, W2, W3);
    hipLaunchKernelGGL(mlp_fused, dim3(NWG), dim3(TPB), 0, stream,
                       ea, b1, b2, b3, W4, b4, out);
}